// Round 6
// baseline (1142.386 us; speedup 1.0000x reference)
//
#include <hip/hip_runtime.h>
#include <hip/hip_bf16.h>
#include <stdint.h>

#define BB 4
#define TT 2048
#define CC 1024
#define HH 8
#define DD 128

typedef unsigned short u16;
typedef unsigned int u32;
typedef unsigned long long u64;
typedef __attribute__((ext_vector_type(4))) float f32x4;
typedef __attribute__((ext_vector_type(16))) float f32x16;
typedef __attribute__((ext_vector_type(8))) __bf16 bf16x8;

__device__ __forceinline__ float bf2f(u16 u){ u32 x=((u32)u)<<16; float f; __builtin_memcpy(&f,&x,4); return f; }
__device__ __forceinline__ u16 f2bf(float f){ u32 x; __builtin_memcpy(&x,&f,4); x += 0x7fffu + ((x>>16)&1u); return (u16)(x>>16); }

__device__ __forceinline__ void gload16(const void* g, void* l){
  __builtin_amdgcn_global_load_lds((const __attribute__((address_space(1))) u32*)g,
                                   (__attribute__((address_space(3))) u32*)l, 16, 0, 0);
}
__device__ __forceinline__ f32x4 mfma16(bf16x8 a, bf16x8 b, f32x4 c){
  return __builtin_amdgcn_mfma_f32_16x16x32_bf16(a,b,c,0,0,0);
}
__device__ __forceinline__ f32x16 mfma32(bf16x8 a, bf16x8 b, f32x16 c){
  return __builtin_amdgcn_mfma_f32_32x32x16_bf16(a,b,c,0,0,0);
}
__device__ __forceinline__ u32 cvtpk(float lo, float hi){
  u32 r; asm("v_cvt_pk_bf16_f32 %0, %1, %2" : "=v"(r) : "v"(lo), "v"(hi)); return r;
}
__device__ __forceinline__ void pl32swap(u32& d, u32& s){
  asm volatile("v_permlane32_swap_b32 %0, %1" : "+v"(d), "+v"(s));
}
union FRAG { u32 u[4]; bf16x8 v; };
union BFV { bf16x8 v; u16 u[8]; };

// ---------------- LayerNorm: f32 x -> bf16 xn ----------------
__global__ void ln_k(const float* __restrict__ x, const float* __restrict__ g,
                     const float* __restrict__ bta, u16* __restrict__ xn){
  int row = blockIdx.x, tid = threadIdx.x;
  const float4 v = ((const float4*)(x + (size_t)row*CC))[tid];
  float s = v.x+v.y+v.z+v.w;
  float ss = v.x*v.x+v.y*v.y+v.z*v.z+v.w*v.w;
  #pragma unroll
  for(int m=1;m<64;m<<=1){ s += __shfl_xor(s,m); ss += __shfl_xor(ss,m); }
  __shared__ float red[8];
  if((tid&63)==0){ red[tid>>6]=s; red[4+(tid>>6)]=ss; }
  __syncthreads();
  float ts = red[0]+red[1]+red[2]+red[3];
  float tss = red[4]+red[5]+red[6]+red[7];
  float mu = ts*(1.0f/CC);
  float rs = rsqrtf(tss*(1.0f/CC) - mu*mu + 1e-5f);
  int c0 = tid*4;
  ushort4 o;
  o.x = f2bf((v.x-mu)*rs*g[c0+0]+bta[c0+0]);
  o.y = f2bf((v.y-mu)*rs*g[c0+1]+bta[c0+1]);
  o.z = f2bf((v.z-mu)*rs*g[c0+2]+bta[c0+2]);
  o.w = f2bf((v.w-mu)*rs*g[c0+3]+bta[c0+3]);
  ((ushort4*)(xn + (size_t)row*CC))[tid] = o;
}

// ---------------- weights f32 -> bf16 ----------------
__global__ void wconv_k(const float* __restrict__ wq, const float* __restrict__ wk,
                        const float* __restrict__ wv, const float* __restrict__ wo,
                        u16* __restrict__ out){
  int i = blockIdx.x*256 + threadIdx.x;
  int sel = i>>18;
  const float* src = sel==0?wq: sel==1?wk: sel==2?wv:wo;
  float4 v = ((const float4*)src)[i & 262143];
  ushort4 o; o.x=f2bf(v.x); o.y=f2bf(v.y); o.z=f2bf(v.z); o.w=f2bf(v.w);
  ((ushort4*)out)[i] = o;
}

// ---------------- RoPE tables ----------------
__global__ void rope_tab_k(float* __restrict__ cosT, float* __restrict__ sinT){
  int i = blockIdx.x*256 + threadIdx.x;
  int t = i>>6, j = i&63;
  float inv = powf(10000.0f, -(float)(2*j)*(1.0f/128.0f));
  float a = (float)t * inv;
  cosT[i] = cosf(a);
  sinT[i] = sinf(a);
}

// ---------------- RoPE apply ----------------
__global__ void rope_apply_k(u16* __restrict__ Qb, u16* __restrict__ Kb,
                             const float* __restrict__ cosT, const float* __restrict__ sinT){
  int bt = blockIdx.x, tid = threadIdx.x;
  int t = bt & (TT-1);
  #pragma unroll
  for(int pp=0; pp<2; pp++){
    int p = tid*2+pp;
    int h = p>>6, d = p&63;
    size_t i1 = (size_t)bt*CC + h*DD + d;
    float c = cosT[t*64+d], s = sinT[t*64+d];
    float q1 = bf2f(Qb[i1]), q2 = bf2f(Qb[i1+64]);
    Qb[i1]    = f2bf(q1*c - q2*s);
    Qb[i1+64] = f2bf(q2*c + q1*s);
    float k1 = bf2f(Kb[i1]), k2 = bf2f(Kb[i1+64]);
    Kb[i1]    = f2bf(k1*c - k2*s);
    Kb[i1+64] = f2bf(k2*c + k1*s);
  }
}

// ---------------- qp/kp ----------------
__global__ void qpkp_k(const u16* __restrict__ Qb, const u16* __restrict__ Kb,
                       const float* __restrict__ dirs, float* __restrict__ qp, float* __restrict__ kp){
  int idx = blockIdx.x*256 + threadIdx.x;
  int b = idx>>14, rem = idx & 16383;
  int h = rem>>11, t = rem & 2047;
  size_t base = ((size_t)(b*TT + t))*CC + h*DD;
  float d0 = dirs[h*3], d1 = dirs[h*3+1], d2 = dirs[h*3+2];
  qp[idx] = bf2f(Qb[base])*d0 + bf2f(Qb[base+1])*d1 + bf2f(Qb[base+2])*d2;
  kp[idx] = bf2f(Kb[base])*d0 + bf2f(Kb[base+1])*d1 + bf2f(Kb[base+2])*d2;
}

// ---------------- GEMM ----------------
template<int MODE>
__global__ __launch_bounds__(256) void gemm_k(const u16* __restrict__ A, const u16* __restrict__ W,
                                              u16* __restrict__ outb, float* __restrict__ outf,
                                              const float* __restrict__ resid){
  __shared__ __align__(16) u16 As[128*64];
  __shared__ __align__(16) u16 Bs[128*64];
  const int K = CC;
  int m0 = blockIdx.x*128, n0 = blockIdx.y*128;
  int tid = threadIdx.x, w = tid>>6, l = tid&63;
  int li = l&15, lg = l>>4;
  int wm = w>>1, wn = w&1;
  f32x4 acc[4][4] = {};
  for(int k0=0; k0<K; k0+=64){
    #pragma unroll
    for(int i=0;i<4;i++){
      int L = (w*4+i)*1024 + l*16;
      int row = L>>7;
      int colb = (L&127) ^ ((row&7)<<4);
      gload16(A + ((size_t)(m0+row)*K + k0 + (colb>>1)), (char*)As + (w*4+i)*1024);
      gload16(W + ((size_t)(n0+row)*K + k0 + (colb>>1)), (char*)Bs + (w*4+i)*1024);
    }
    __syncthreads();
    #pragma unroll
    for(int kc=0;kc<2;kc++){
      bf16x8 af[4], bfr[4];
      #pragma unroll
      for(int mi=0;mi<4;mi++){
        int row = wm*64 + mi*16 + li;
        int colb = (kc*64 + lg*16) ^ ((row&7)<<4);
        af[mi] = *(const bf16x8*)((const char*)As + row*128 + colb);
      }
      #pragma unroll
      for(int ni=0;ni<4;ni++){
        int row = wn*64 + ni*16 + li;
        int colb = (kc*64 + lg*16) ^ ((row&7)<<4);
        bfr[ni] = *(const bf16x8*)((const char*)Bs + row*128 + colb);
      }
      #pragma unroll
      for(int mi=0;mi<4;mi++){
        #pragma unroll
        for(int ni=0;ni<4;ni++)
          acc[mi][ni] = mfma16(af[mi], bfr[ni], acc[mi][ni]);
      }
    }
    __syncthreads();
  }
  #pragma unroll
  for(int mi=0;mi<4;mi++){
    #pragma unroll
    for(int ni=0;ni<4;ni++){
      #pragma unroll
      for(int r=0;r<4;r++){
        int row = m0 + wm*64 + mi*16 + lg*4 + r;
        int col = n0 + wn*64 + ni*16 + li;
        float v = acc[mi][ni][r];
        if(MODE==0){
          outb[(size_t)row*CC + col] = f2bf(v);
        } else if(MODE==1){
          int hh = col>>7, dd = col&127, bb = row>>11, t = row&2047;
          outb[(((size_t)bb*HH+hh)*DD+dd)*TT + t] = f2bf(v);
        } else {
          size_t o = (size_t)row*CC + col;
          outf[o] = v + resid[o];
        }
      }
    }
  }
}

// ---------------- fused dual flash attention: R4 body + optional k-split partials ----------------
// SPLIT=0: 1024 blocks x 128 (R4-exact: full k-range, direct normalized write).
// SPLIT=1: 1536 blocks x 128. Per-wave unit u = (r>>2)*2 + w:
//   u<64 : strip j = 63-(u>>1) (j>=32), half = u&1 -> k-subtiles [0,mid) / [mid,n); write RAW partials.
//   u>=64: strip j = 95-u (j<32), full range, direct normalized write.
template<int SPLIT>
__global__ __launch_bounds__(128,3) void attn_k(const u16* __restrict__ Q, const u16* __restrict__ Kb,
                                                const u16* __restrict__ VT, const float* __restrict__ qp,
                                                const float* __restrict__ kp, const float* __restrict__ hs,
                                                u16* __restrict__ outp, u16* __restrict__ pO1,
                                                u16* __restrict__ pO2, float4* __restrict__ pml){
  int bid = blockIdx.x;
  int xcd = bid&7, r = bid>>3;
  int tid = threadIdx.x, w = tid>>6, l = tid&63;
  int l5 = l>>5, q31 = l&31;
  int bh = xcd*4 + (r&3);
  int b = bh>>3, h = bh&7;
  int q0, klo, khi, unit = -1;
  if(SPLIT==0){
    int strip = 31 - (r>>2);
    q0 = strip*64 + w*32;
    klo = 0; khi = (q0>>5)+1;
  } else {
    int u = (r>>2)*2 + w;
    if(u < 64){
      int j = 63 - (u>>1), half = u&1;
      int n = j+1, mid = (n+1)>>1;
      q0 = j*32; klo = half? mid : 0; khi = half? n : mid;
      unit = (bh*32 + (j-32))*2 + half;
    } else {
      int j = 95 - u;
      q0 = j*32; klo = 0; khi = j+1;
    }
  }
  int q = q0 + q31;

  // Q fragment (B-operand): outer q, contraction d
  bf16x8 qf[8];
  {
    const u16* qbase = Q + ((size_t)(b*TT + q)*CC + h*DD);
    #pragma unroll
    for(int db=0;db<8;db++) qf[db] = *(const bf16x8*)(qbase + db*16 + l5*8);
  }
  const float L2E = 1.442695040888963f;
  const float sl2 = 0.08838834764831845f * L2E;
  bf16x8 qpf;
  {
    float qs = qp[(size_t)bh*TT + q] * L2E;
    u16 qh = f2bf(qs); float qhf = bf2f(qh);
    u16 ql = f2bf(qs - qhf);
    FRAG fq; fq.u[0] = l5? 0u : ((u32)qh | ((u32)qh<<16));
    fq.u[1] = l5? 0u : (u32)ql; fq.u[2]=0; fq.u[3]=0;
    qpf = fq.v;
  }

  const u16* kcur = Kb + ((size_t)b*TT + klo*32 + q31)*CC + h*DD + l5*8;
  const u16* vt0 = VT + ((size_t)bh*DD +  0 + q31)*TT + l5*8;
  const u16* vt1 = VT + ((size_t)bh*DD + 32 + q31)*TT + l5*8;
  const u16* vt2 = VT + ((size_t)bh*DD + 64 + q31)*TT + l5*8;
  const u16* vt3 = VT + ((size_t)bh*DD + 96 + q31)*TT + l5*8;
  const float* kpp = kp + (size_t)bh*TT + q31;

  float m1=-__builtin_inff(), l1=0.f, m2=-__builtin_inff(), l2=0.f;
  f32x16 a1[4] = {}, a2[4] = {};
  const f32x16 zf = {};

  for(int is=klo; is<khi; ++is){
    int ksub = is*32;

    // ---- K fragments straight from global (L2) ----
    bf16x8 kf0 = *(const bf16x8*)(kcur +   0);
    bf16x8 kf1 = *(const bf16x8*)(kcur +  16);
    bf16x8 kf2 = *(const bf16x8*)(kcur +  32);
    bf16x8 kf3 = *(const bf16x8*)(kcur +  48);
    bf16x8 kf4 = *(const bf16x8*)(kcur +  64);
    bf16x8 kf5 = *(const bf16x8*)(kcur +  80);
    bf16x8 kf6 = *(const bf16x8*)(kcur +  96);
    bf16x8 kf7 = *(const bf16x8*)(kcur + 112);
    kcur += (size_t)32*CC;

    // ---- S^T = K·Q^T (two independent chains) ----
    f32x16 s0 = zf, s1a = zf;
    __builtin_amdgcn_s_setprio(1);
    s0  = mfma32(kf0, qf[0], s0);  s1a = mfma32(kf1, qf[1], s1a);
    s0  = mfma32(kf2, qf[2], s0);  s1a = mfma32(kf3, qf[3], s1a);
    s0  = mfma32(kf4, qf[4], s0);  s1a = mfma32(kf5, qf[5], s1a);
    s0  = mfma32(kf6, qf[6], s0);  s1a = mfma32(kf7, qf[7], s1a);
    __builtin_amdgcn_s_setprio(0);

    // ---- geo scores via rank-1 mfma (hi/lo split, log2 domain) ----
    f32x16 gg;
    {
      float kpv = kpp[ksub];
      u16 kh = f2bf(kpv); float khf = bf2f(kh);
      u16 kl = f2bf(kpv - khf);
      FRAG fk; fk.u[0] = l5? 0u : ((u32)kh | ((u32)kl<<16));
      fk.u[1] = l5? 0u : (u32)kh; fk.u[2]=0; fk.u[3]=0;
      gg = mfma32(fk.v, qpf, zf);
    }

    // ---- scale (+ causal mask only on the diagonal subtile) ----
    float sv[16], gv[16];
    #pragma unroll
    for(int rr=0;rr<16;rr++){ sv[rr] = (s0[rr]+s1a[rr])*sl2; gv[rr] = gg[rr]; }
    if(ksub + 31 > q0){                       // wave-uniform diagonal test
      #pragma unroll
      for(int rr=0;rr<16;rr++){
        int kg = ksub + (rr&3) + 8*(rr>>2) + 4*l5;
        if(kg > q){ sv[rr] = -__builtin_inff(); gv[rr] = -__builtin_inff(); }
      }
    }

    // ---- dual online softmax, lane-local q, defer-max (THR=8 in log2) ----
    float mx=-__builtin_inff(), gx=-__builtin_inff();
    #pragma unroll
    for(int rr=0;rr<16;rr++){ mx = fmaxf(mx, sv[rr]); gx = fmaxf(gx, gv[rr]); }
    mx = fmaxf(mx, __shfl_xor(mx,32));
    gx = fmaxf(gx, __shfl_xor(gx,32));
    if(__ballot((mx > m1+8.f) | (gx > m2+8.f))){
      float mn1 = fmaxf(m1,mx), mn2 = fmaxf(m2,gx);
      float c1 = exp2f(m1-mn1), c2 = exp2f(m2-mn2);
      l1 *= c1; l2 *= c2; m1 = mn1; m2 = mn2;
      #pragma unroll
      for(int dt=0;dt<4;dt++){ a1[dt] *= c1; a2[dt] *= c2; }
    }
    float rs1=0.f, rs2=0.f;
    float e1[16], e2[16];
    #pragma unroll
    for(int rr=0;rr<16;rr++){
      e1[rr] = exp2f(sv[rr] - m1); rs1 += e1[rr];
      e2[rr] = exp2f(gv[rr] - m2); rs2 += e2[rr];
    }
    rs1 += __shfl_xor(rs1,32); rs2 += __shfl_xor(rs2,32);
    l1 += rs1; l2 += rs2;

    // ---- P -> bf16 B-fragments in-register ----
    u32 P1[8], P2[8];
    #pragma unroll
    for(int m=0;m<8;m++){ P1[m] = cvtpk(e1[2*m], e1[2*m+1]); P2[m] = cvtpk(e2[2*m], e2[2*m+1]); }
    pl32swap(P1[0],P1[2]); pl32swap(P1[1],P1[3]); pl32swap(P1[4],P1[6]); pl32swap(P1[5],P1[7]);
    pl32swap(P2[0],P2[2]); pl32swap(P2[1],P2[3]); pl32swap(P2[4],P2[6]); pl32swap(P2[5],P2[7]);

    // ---- O^T += V^T · P^T (V fragments straight from global) ----
    #pragma unroll
    for(int kb2=0;kb2<2;kb2++){
      FRAG f1, f2;
      #pragma unroll
      for(int j2=0;j2<4;j2++){ f1.u[j2] = P1[kb2*4+j2]; f2.u[j2] = P2[kb2*4+j2]; }
      bf16x8 pb1 = f1.v, pb2 = f2.v;
      int ko = ksub + kb2*16;
      bf16x8 vf0 = *(const bf16x8*)(vt0 + ko);
      bf16x8 vf1 = *(const bf16x8*)(vt1 + ko);
      bf16x8 vf2 = *(const bf16x8*)(vt2 + ko);
      bf16x8 vf3 = *(const bf16x8*)(vt3 + ko);
      __builtin_amdgcn_s_setprio(1);
      a1[0] = mfma32(vf0, pb1, a1[0]);  a2[0] = mfma32(vf0, pb2, a2[0]);
      a1[1] = mfma32(vf1, pb1, a1[1]);  a2[1] = mfma32(vf1, pb2, a2[1]);
      a1[2] = mfma32(vf2, pb1, a1[2]);  a2[2] = mfma32(vf2, pb2, a2[2]);
      a1[3] = mfma32(vf3, pb1, a1[3]);  a2[3] = mfma32(vf3, pb2, a2[3]);
      __builtin_amdgcn_s_setprio(0);
    }
  }

  if(unit < 0){
    // direct: normalize + mix + write xn
    float rl1 = 1.0f/l1, rl2 = 1.0f/l2;
    float sh = hs[h];
    u16* obase = outp + (size_t)(b*TT + q)*CC + h*DD;
    #pragma unroll
    for(int dt=0;dt<4;dt++){
      #pragma unroll
      for(int m=0;m<8;m++){
        float oa1 = a1[dt][2*m]*rl1,   oa2 = a2[dt][2*m]*rl2;
        float ob1 = a1[dt][2*m+1]*rl1, ob2 = a2[dt][2*m+1]*rl2;
        float oa = oa1 + sh*(oa2-oa1);
        float ob = ob1 + sh*(ob2-ob1);
        int d = dt*32 + (2*m&3) + 8*(m>>1) + 4*l5;
        *(u32*)(obase + d) = cvtpk(oa, ob);
      }
    }
  } else {
    // partial: raw (unnormalized) O~ as bf16 + (m,l) per row
    size_t base = ((size_t)unit*32 + q31)*128;
    #pragma unroll
    for(int dt=0;dt<4;dt++){
      #pragma unroll
      for(int m=0;m<8;m++){
        int d = dt*32 + (2*m&3) + 8*(m>>1) + 4*l5;
        *(u32*)(pO1 + base + d) = cvtpk(a1[dt][2*m], a1[dt][2*m+1]);
        *(u32*)(pO2 + base + d) = cvtpk(a2[dt][2*m], a2[dt][2*m+1]);
      }
    }
    if(l5==0) pml[(size_t)unit*32 + q31] = make_float4(m1, l1, m2, l2);
  }
}

// ---------------- combine k-split partials (rows with j>=32, i.e. q>=1024 per bh) ----------------
__global__ __launch_bounds__(256) void comb_k(const u16* __restrict__ pO1, const u16* __restrict__ pO2,
                                              const float4* __restrict__ pml, const float* __restrict__ hs,
                                              u16* __restrict__ outp){
  int gt = blockIdx.x*256 + threadIdx.x;     // 0..131071
  int rowid = gt>>2, chunk = gt&3;
  int bh = rowid>>10, qq = rowid & 1023;
  int q = 1024 + qq;
  int j = q>>5, q31 = q&31;
  int b = bh>>3, h = bh&7;
  int ub = (bh*32 + (j-32))*2;
  float4 A = pml[(size_t)(ub+0)*32 + q31];
  float4 Bm = pml[(size_t)(ub+1)*32 + q31];
  float m1m = fmaxf(A.x, Bm.x);
  float w10 = exp2f(A.x - m1m), w11 = exp2f(Bm.x - m1m);
  float r1 = 1.f/(w10*A.y + w11*Bm.y);
  float m2m = fmaxf(A.z, Bm.z);
  float w20 = exp2f(A.z - m2m), w21 = exp2f(Bm.z - m2m);
  float r2 = 1.f/(w20*A.w + w21*Bm.w);
  float sh = hs[h];
  size_t p0 = ((size_t)(ub+0)*32 + q31)*128 + chunk*32;
  size_t p1 = ((size_t)(ub+1)*32 + q31)*128 + chunk*32;
  u16* ob = outp + ((size_t)(b*TT + q))*CC + h*DD + chunk*32;
  #pragma unroll
  for(int v=0;v<4;v++){
    BFV a10, a11, a20, a21;
    a10.v = *(const bf16x8*)(pO1 + p0 + v*8);
    a11.v = *(const bf16x8*)(pO1 + p1 + v*8);
    a20.v = *(const bf16x8*)(pO2 + p0 + v*8);
    a21.v = *(const bf16x8*)(pO2 + p1 + v*8);
    union { u16 o[8]; uint4 q4; } out;
    #pragma unroll
    for(int e=0;e<8;e++){
      float o1 = (w10*bf2f(a10.u[e]) + w11*bf2f(a11.u[e]))*r1;
      float o2 = (w20*bf2f(a20.u[e]) + w21*bf2f(a21.u[e]))*r2;
      out.o[e] = f2bf(o1 + sh*(o2-o1));
    }
    *(uint4*)(ob + v*8) = out.q4;
  }
}

extern "C" void kernel_launch(void* const* d_in, const int* in_sizes, int n_in,
                              void* d_out, int out_size, void* d_ws, size_t ws_size,
                              hipStream_t stream){
  (void)in_sizes; (void)n_in; (void)out_size;
  const float* x   = (const float*)d_in[0];
  const float* Wq  = (const float*)d_in[1];
  const float* Wk  = (const float*)d_in[2];
  const float* Wv  = (const float*)d_in[3];
  const float* Wo  = (const float*)d_in[4];
  const float* lng = (const float*)d_in[5];
  const float* lnb = (const float*)d_in[6];
  const float* hsc = (const float*)d_in[7];
  const float* hdr = (const float*)d_in[8];

  char* ws = (char*)d_ws;
  const size_t SZ = (size_t)8192*1024*2;
  u16* xn   = (u16*)ws;
  u16* wbf  = (u16*)(ws + SZ);
  u16* Qb   = (u16*)(ws + SZ + 8388608);
  u16* Kb   = (u16*)(ws + 2*SZ + 8388608);
  u16* VT   = (u16*)(ws + 3*SZ + 8388608);
  float* cosT = (float*)(ws + 4*SZ + 8388608);
  float* sinT = cosT + 131072;
  float* qp   = sinT + 131072;
  float* kp   = qp + 65536;
  u16* pO1    = (u16*)(ws + 77070336);
  u16* pO2    = (u16*)(ws + 93847552);
  float4* pml = (float4*)(ws + 110624768);
  const size_t NEED = 111673344;

  ln_k<<<8192,256,0,stream>>>(x, lng, lnb, xn);
  wconv_k<<<4096,256,0,stream>>>(Wq,Wk,Wv,Wo,wbf);
  rope_tab_k<<<512,256,0,stream>>>(cosT,sinT);
  gemm_k<0><<<dim3(64,8),256,0,stream>>>(xn, wbf,          Qb, nullptr, nullptr);
  gemm_k<0><<<dim3(64,8),256,0,stream>>>(xn, wbf+1048576,  Kb, nullptr, nullptr);
  gemm_k<1><<<dim3(64,8),256,0,stream>>>(xn, wbf+2097152,  VT, nullptr, nullptr);
  rope_apply_k<<<8192,256,0,stream>>>(Qb,Kb,cosT,sinT);
  qpkp_k<<<256,256,0,stream>>>(Qb,Kb,hdr,qp,kp);
  if(ws_size >= NEED){
    attn_k<1><<<1536,128,0,stream>>>(Qb,Kb,VT,qp,kp,hsc,xn,pO1,pO2,pml);
    comb_k<<<512,256,0,stream>>>(pO1,pO2,pml,hsc,xn);
  } else {
    attn_k<0><<<1024,128,0,stream>>>(Qb,Kb,VT,qp,kp,hsc,xn,nullptr,nullptr,nullptr);
  }
  gemm_k<2><<<dim3(64,8),256,0,stream>>>(xn, wbf+3145728, nullptr, (float*)d_out, x);
}

// Round 7
// 1048.199 us; speedup vs baseline: 1.0899x; 1.0899x over previous
//
#include <hip/hip_runtime.h>
#include <hip/hip_bf16.h>
#include <stdint.h>

#define BB 4
#define TT 2048
#define CC 1024
#define HH 8
#define DD 128

typedef unsigned short u16;
typedef unsigned int u32;
typedef unsigned long long u64;
typedef __attribute__((ext_vector_type(4))) float f32x4;
typedef __attribute__((ext_vector_type(16))) float f32x16;
typedef __attribute__((ext_vector_type(8))) __bf16 bf16x8;

__device__ __forceinline__ float bf2f(u16 u){ u32 x=((u32)u)<<16; float f; __builtin_memcpy(&f,&x,4); return f; }
__device__ __forceinline__ u16 f2bf(float f){ u32 x; __builtin_memcpy(&x,&f,4); x += 0x7fffu + ((x>>16)&1u); return (u16)(x>>16); }

__device__ __forceinline__ void gload16(const void* g, void* l){
  __builtin_amdgcn_global_load_lds((const __attribute__((address_space(1))) u32*)g,
                                   (__attribute__((address_space(3))) u32*)l, 16, 0, 0);
}
__device__ __forceinline__ f32x4 mfma16(bf16x8 a, bf16x8 b, f32x4 c){
  return __builtin_amdgcn_mfma_f32_16x16x32_bf16(a,b,c,0,0,0);
}
__device__ __forceinline__ f32x16 mfma32(bf16x8 a, bf16x8 b, f32x16 c){
  return __builtin_amdgcn_mfma_f32_32x32x16_bf16(a,b,c,0,0,0);
}
__device__ __forceinline__ u32 cvtpk(float lo, float hi){
  u32 r; asm("v_cvt_pk_bf16_f32 %0, %1, %2" : "=v"(r) : "v"(lo), "v"(hi)); return r;
}
__device__ __forceinline__ void pl32swap(u32& d, u32& s){
  asm volatile("v_permlane32_swap_b32 %0, %1" : "+v"(d), "+v"(s));
}
union FRAG { u32 u[4]; bf16x8 v; };

// ---------------- LayerNorm: f32 x -> bf16 xn ----------------
__global__ void ln_k(const float* __restrict__ x, const float* __restrict__ g,
                     const float* __restrict__ bta, u16* __restrict__ xn){
  int row = blockIdx.x, tid = threadIdx.x;
  const float4 v = ((const float4*)(x + (size_t)row*CC))[tid];
  float s = v.x+v.y+v.z+v.w;
  float ss = v.x*v.x+v.y*v.y+v.z*v.z+v.w*v.w;
  #pragma unroll
  for(int m=1;m<64;m<<=1){ s += __shfl_xor(s,m); ss += __shfl_xor(ss,m); }
  __shared__ float red[8];
  if((tid&63)==0){ red[tid>>6]=s; red[4+(tid>>6)]=ss; }
  __syncthreads();
  float ts = red[0]+red[1]+red[2]+red[3];
  float tss = red[4]+red[5]+red[6]+red[7];
  float mu = ts*(1.0f/CC);
  float rs = rsqrtf(tss*(1.0f/CC) - mu*mu + 1e-5f);
  int c0 = tid*4;
  ushort4 o;
  o.x = f2bf((v.x-mu)*rs*g[c0+0]+bta[c0+0]);
  o.y = f2bf((v.y-mu)*rs*g[c0+1]+bta[c0+1]);
  o.z = f2bf((v.z-mu)*rs*g[c0+2]+bta[c0+2]);
  o.w = f2bf((v.w-mu)*rs*g[c0+3]+bta[c0+3]);
  ((ushort4*)(xn + (size_t)row*CC))[tid] = o;
}

// ---------------- weights f32 -> bf16 ----------------
__global__ void wconv_k(const float* __restrict__ wq, const float* __restrict__ wk,
                        const float* __restrict__ wv, const float* __restrict__ wo,
                        u16* __restrict__ out){
  int i = blockIdx.x*256 + threadIdx.x;
  int sel = i>>18;
  const float* src = sel==0?wq: sel==1?wk: sel==2?wv:wo;
  float4 v = ((const float4*)src)[i & 262143];
  ushort4 o; o.x=f2bf(v.x); o.y=f2bf(v.y); o.z=f2bf(v.z); o.w=f2bf(v.w);
  ((ushort4*)out)[i] = o;
}

// ---------------- RoPE tables ----------------
__global__ void rope_tab_k(float* __restrict__ cosT, float* __restrict__ sinT){
  int i = blockIdx.x*256 + threadIdx.x;
  int t = i>>6, j = i&63;
  float inv = powf(10000.0f, -(float)(2*j)*(1.0f/128.0f));
  float a = (float)t * inv;
  cosT[i] = cosf(a);
  sinT[i] = sinf(a);
}

// ---------------- qp/kp from RAW Q,K (rope applied locally to dims 0..2) ----------------
__global__ void qpkp_k(const u16* __restrict__ Qb, const u16* __restrict__ Kb,
                       const float* __restrict__ dirs, const float* __restrict__ cosT,
                       const float* __restrict__ sinT, float* __restrict__ qp, float* __restrict__ kp){
  int idx = blockIdx.x*256 + threadIdx.x;   // (b*H+h)*T + t
  int b = idx>>14, rem = idx & 16383;
  int h = rem>>11, t = rem & 2047;
  size_t base = ((size_t)(b*TT + t))*CC + h*DD;
  float qv = 0.f, kv = 0.f;
  #pragma unroll
  for(int d=0; d<3; d++){
    float c = cosT[t*64+d], s = sinT[t*64+d];
    float dr = dirs[h*3+d];
    qv += (bf2f(Qb[base+d])*c - bf2f(Qb[base+d+64])*s) * dr;
    kv += (bf2f(Kb[base+d])*c - bf2f(Kb[base+d+64])*s) * dr;
  }
  qp[idx] = qv; kp[idx] = kv;
}

// ---------------- RoPE: Q in place; K rope + pack into fragment-ordered KF ----------------
// KF u16 idx = ((bh*64 + ks)*8 + (d>>4))*512 + (((d>>3)&1)*32 + k31)*8 + (d&7)
__global__ void ropepack_k(u16* __restrict__ Qb, const u16* __restrict__ Kb,
                           u16* __restrict__ KF,
                           const float* __restrict__ cosT, const float* __restrict__ sinT){
  int bt = blockIdx.x, tid = threadIdx.x;   // 8192 x 128
  int b = bt>>11, t = bt & (TT-1);
  int ks = t>>5, k31 = t&31;
  #pragma unroll
  for(int pp=0; pp<4; pp++){
    int p = tid*4+pp;          // 0..511 = (h, d<64)
    int h = p>>6, d = p&63;
    size_t i1 = (size_t)bt*CC + h*DD + d;
    float c = cosT[t*64+d], s = sinT[t*64+d];
    float q1 = bf2f(Qb[i1]), q2 = bf2f(Qb[i1+64]);
    Qb[i1]    = f2bf(q1*c - q2*s);
    Qb[i1+64] = f2bf(q2*c + q1*s);
    float k1 = bf2f(Kb[i1]), k2 = bf2f(Kb[i1+64]);
    u16 kr1 = f2bf(k1*c - k2*s);
    u16 kr2 = f2bf(k2*c + k1*s);
    int bh = b*HH + h;
    int d2 = d + 64;
    size_t o1 = (((size_t)(bh*64 + ks)*8) + (d >>4))*512 + (((d >>3)&1)*32 + k31)*8 + (d &7);
    size_t o2 = (((size_t)(bh*64 + ks)*8) + (d2>>4))*512 + (((d2>>3)&1)*32 + k31)*8 + (d2&7);
    KF[o1] = kr1;
    KF[o2] = kr2;
  }
}

// ---------------- GEMM ----------------
// MODE 0: bf16 row-major out. MODE 4: bf16 out packed to V-fragment order VF. MODE 2: f32 out + resid.
template<int MODE>
__global__ __launch_bounds__(256) void gemm_k(const u16* __restrict__ A, const u16* __restrict__ W,
                                              u16* __restrict__ outb, float* __restrict__ outf,
                                              const float* __restrict__ resid){
  __shared__ __align__(16) u16 As[128*64];
  __shared__ __align__(16) u16 Bs[128*64];
  const int K = CC;
  int m0 = blockIdx.x*128, n0 = blockIdx.y*128;
  int tid = threadIdx.x, w = tid>>6, l = tid&63;
  int li = l&15, lg = l>>4;
  int wm = w>>1, wn = w&1;
  f32x4 acc[4][4] = {};
  for(int k0=0; k0<K; k0+=64){
    #pragma unroll
    for(int i=0;i<4;i++){
      int L = (w*4+i)*1024 + l*16;
      int row = L>>7;
      int colb = (L&127) ^ ((row&7)<<4);
      gload16(A + ((size_t)(m0+row)*K + k0 + (colb>>1)), (char*)As + (w*4+i)*1024);
      gload16(W + ((size_t)(n0+row)*K + k0 + (colb>>1)), (char*)Bs + (w*4+i)*1024);
    }
    __syncthreads();
    #pragma unroll
    for(int kc=0;kc<2;kc++){
      bf16x8 af[4], bfr[4];
      #pragma unroll
      for(int mi=0;mi<4;mi++){
        int row = wm*64 + mi*16 + li;
        int colb = (kc*64 + lg*16) ^ ((row&7)<<4);
        af[mi] = *(const bf16x8*)((const char*)As + row*128 + colb);
      }
      #pragma unroll
      for(int ni=0;ni<4;ni++){
        int row = wn*64 + ni*16 + li;
        int colb = (kc*64 + lg*16) ^ ((row&7)<<4);
        bfr[ni] = *(const bf16x8*)((const char*)Bs + row*128 + colb);
      }
      #pragma unroll
      for(int mi=0;mi<4;mi++){
        #pragma unroll
        for(int ni=0;ni<4;ni++)
          acc[mi][ni] = mfma16(af[mi], bfr[ni], acc[mi][ni]);
      }
    }
    __syncthreads();
  }
  #pragma unroll
  for(int mi=0;mi<4;mi++){
    #pragma unroll
    for(int ni=0;ni<4;ni++){
      #pragma unroll
      for(int r=0;r<4;r++){
        int row = m0 + wm*64 + mi*16 + lg*4 + r;
        int col = n0 + wn*64 + ni*16 + li;
        float v = acc[mi][ni][r];
        if(MODE==0){
          outb[(size_t)row*CC + col] = f2bf(v);
        } else if(MODE==4){
          // V-fragment pack: VF[((bh*64+ks)*8 + (d>>5)*2 + ((t>>4)&1))*512 + (((t>>3)&1)*32 + (d&31))*8 + (t&7)]
          int t = row & 2047, b = row>>11;
          int h = col>>7, d = col&127;
          int bh = b*HH + h;
          size_t o = (((size_t)(bh*64 + (t>>5))*8) + (d>>5)*2 + ((t>>4)&1))*512
                     + (((t>>3)&1)*32 + (d&31))*8 + (t&7);
          outb[o] = f2bf(v);
        } else {
          size_t o = (size_t)row*CC + col;
          outf[o] = v + resid[o];
        }
      }
    }
  }
}

// ---------------- fused dual flash attention: R4 structure + fragment-packed K/V ----------------
// 1024 blocks x 128 thr (2 waves). Block -> (bh, strip of 64 q); wave w owns 32 q.
// All K/V loads are contiguous 1KB bursts from the fragment-ordered KF/VF buffers.
__global__ __launch_bounds__(128,3) void attn_k(const u16* __restrict__ Q, const u16* __restrict__ KF,
                                                const u16* __restrict__ VF, const float* __restrict__ qp,
                                                const float* __restrict__ kp, const float* __restrict__ hs,
                                                u16* __restrict__ outp){
  int bid = blockIdx.x;
  int xcd = bid&7, r = bid>>3;          // r: 0..127
  int bh = xcd*4 + (r&3);               // 4 bh groups per XCD (K/V L2-resident)
  int strip = 31 - (r>>2);              // 31..0: longest strips dispatch first
  int b = bh>>3, h = bh&7;
  int tid = threadIdx.x, w = tid>>6, l = tid&63;
  int l5 = l>>5, q31 = l&31;
  int q0 = strip*64 + w*32;
  int q  = q0 + q31;
  int nsub = (q0>>5) + 1;               // 32-k subtiles this wave needs

  // Q fragment (B-operand): outer q, contraction d
  bf16x8 qf[8];
  {
    const u16* qbase = Q + ((size_t)(b*TT + q)*CC + h*DD);
    #pragma unroll
    for(int db=0;db<8;db++) qf[db] = *(const bf16x8*)(qbase + db*16 + l5*8);
  }
  const float L2E = 1.442695040888963f;
  const float sl2 = 0.08838834764831845f * L2E;
  bf16x8 qpf;
  {
    float qs = qp[(size_t)bh*TT + q] * L2E;
    u16 qh = f2bf(qs); float qhf = bf2f(qh);
    u16 ql = f2bf(qs - qhf);
    FRAG fq; fq.u[0] = l5? 0u : ((u32)qh | ((u32)qh<<16));
    fq.u[1] = l5? 0u : (u32)ql; fq.u[2]=0; fq.u[3]=0;
    qpf = fq.v;
  }

  // fragment-stream pointers: 4096 u16 (8KB) per subtile per buffer
  const u16* kfp = KF + (size_t)bh*64*4096 + (size_t)l*8;
  const u16* vfp = VF + (size_t)bh*64*4096 + (size_t)l*8;
  const float* kpp = kp + (size_t)bh*TT + q31;

  float m1=-__builtin_inff(), l1=0.f, m2=-__builtin_inff(), l2=0.f;
  f32x16 a1[4] = {}, a2[4] = {};
  const f32x16 zf = {};

  for(int is=0; is<nsub; ++is){
    int ksub = is*32;

    // ---- K fragments: 8 contiguous 1KB bursts ----
    bf16x8 kf0 = *(const bf16x8*)(kfp + 0*512);
    bf16x8 kf1 = *(const bf16x8*)(kfp + 1*512);
    bf16x8 kf2 = *(const bf16x8*)(kfp + 2*512);
    bf16x8 kf3 = *(const bf16x8*)(kfp + 3*512);
    bf16x8 kf4 = *(const bf16x8*)(kfp + 4*512);
    bf16x8 kf5 = *(const bf16x8*)(kfp + 5*512);
    bf16x8 kf6 = *(const bf16x8*)(kfp + 6*512);
    bf16x8 kf7 = *(const bf16x8*)(kfp + 7*512);

    // ---- S^T = K·Q^T (two independent chains) ----
    f32x16 s0 = zf, s1a = zf;
    __builtin_amdgcn_s_setprio(1);
    s0  = mfma32(kf0, qf[0], s0);  s1a = mfma32(kf1, qf[1], s1a);
    s0  = mfma32(kf2, qf[2], s0);  s1a = mfma32(kf3, qf[3], s1a);
    s0  = mfma32(kf4, qf[4], s0);  s1a = mfma32(kf5, qf[5], s1a);
    s0  = mfma32(kf6, qf[6], s0);  s1a = mfma32(kf7, qf[7], s1a);
    __builtin_amdgcn_s_setprio(0);

    // ---- geo scores via rank-1 mfma (hi/lo split, log2 domain) ----
    f32x16 gg;
    {
      float kpv = kpp[ksub];
      u16 kh = f2bf(kpv); float khf = bf2f(kh);
      u16 kl = f2bf(kpv - khf);
      FRAG fk; fk.u[0] = l5? 0u : ((u32)kh | ((u32)kl<<16));
      fk.u[1] = l5? 0u : (u32)kh; fk.u[2]=0; fk.u[3]=0;
      gg = mfma32(fk.v, qpf, zf);
    }

    // ---- scale (+ causal mask only on the diagonal subtile) ----
    float sv[16], gv[16];
    #pragma unroll
    for(int rr=0;rr<16;rr++){ sv[rr] = (s0[rr]+s1a[rr])*sl2; gv[rr] = gg[rr]; }
    if(ksub + 31 > q0){                       // wave-uniform diagonal test
      #pragma unroll
      for(int rr=0;rr<16;rr++){
        int kg = ksub + (rr&3) + 8*(rr>>2) + 4*l5;
        if(kg > q){ sv[rr] = -__builtin_inff(); gv[rr] = -__builtin_inff(); }
      }
    }

    // ---- dual online softmax, lane-local q, defer-max (THR=8 in log2) ----
    float mx=-__builtin_inff(), gx=-__builtin_inff();
    #pragma unroll
    for(int rr=0;rr<16;rr++){ mx = fmaxf(mx, sv[rr]); gx = fmaxf(gx, gv[rr]); }
    mx = fmaxf(mx, __shfl_xor(mx,32));
    gx = fmaxf(gx, __shfl_xor(gx,32));
    if(__ballot((mx > m1+8.f) | (gx > m2+8.f))){
      float mn1 = fmaxf(m1,mx), mn2 = fmaxf(m2,gx);
      float c1 = exp2f(m1-mn1), c2 = exp2f(m2-mn2);
      l1 *= c1; l2 *= c2; m1 = mn1; m2 = mn2;
      #pragma unroll
      for(int dt=0;dt<4;dt++){ a1[dt] *= c1; a2[dt] *= c2; }
    }
    float rs1=0.f, rs2=0.f;
    float e1[16], e2[16];
    #pragma unroll
    for(int rr=0;rr<16;rr++){
      e1[rr] = exp2f(sv[rr] - m1); rs1 += e1[rr];
      e2[rr] = exp2f(gv[rr] - m2); rs2 += e2[rr];
    }
    rs1 += __shfl_xor(rs1,32); rs2 += __shfl_xor(rs2,32);
    l1 += rs1; l2 += rs2;

    // ---- P -> bf16 B-fragments in-register ----
    u32 P1[8], P2[8];
    #pragma unroll
    for(int m=0;m<8;m++){ P1[m] = cvtpk(e1[2*m], e1[2*m+1]); P2[m] = cvtpk(e2[2*m], e2[2*m+1]); }
    pl32swap(P1[0],P1[2]); pl32swap(P1[1],P1[3]); pl32swap(P1[4],P1[6]); pl32swap(P1[5],P1[7]);
    pl32swap(P2[0],P2[2]); pl32swap(P2[1],P2[3]); pl32swap(P2[4],P2[6]); pl32swap(P2[5],P2[7]);

    // ---- O^T += V^T · P^T (V fragments: contiguous 1KB bursts) ----
    #pragma unroll
    for(int kb2=0;kb2<2;kb2++){
      FRAG f1, f2;
      #pragma unroll
      for(int j2=0;j2<4;j2++){ f1.u[j2] = P1[kb2*4+j2]; f2.u[j2] = P2[kb2*4+j2]; }
      bf16x8 pb1 = f1.v, pb2 = f2.v;
      bf16x8 vf0 = *(const bf16x8*)(vfp + (0+kb2)*512);
      bf16x8 vf1 = *(const bf16x8*)(vfp + (2+kb2)*512);
      bf16x8 vf2 = *(const bf16x8*)(vfp + (4+kb2)*512);
      bf16x8 vf3 = *(const bf16x8*)(vfp + (6+kb2)*512);
      __builtin_amdgcn_s_setprio(1);
      a1[0] = mfma32(vf0, pb1, a1[0]);  a2[0] = mfma32(vf0, pb2, a2[0]);
      a1[1] = mfma32(vf1, pb1, a1[1]);  a2[1] = mfma32(vf1, pb2, a2[1]);
      a1[2] = mfma32(vf2, pb1, a1[2]);  a2[2] = mfma32(vf2, pb2, a2[2]);
      a1[3] = mfma32(vf3, pb1, a1[3]);  a2[3] = mfma32(vf3, pb2, a2[3]);
      __builtin_amdgcn_s_setprio(0);
    }
    kfp += 4096; vfp += 4096;
  }

  float rl1 = 1.0f/l1, rl2 = 1.0f/l2;
  float sh = hs[h];
  u16* obase = outp + (size_t)(b*TT + q)*CC + h*DD;
  #pragma unroll
  for(int dt=0;dt<4;dt++){
    #pragma unroll
    for(int m=0;m<8;m++){
      float oa1 = a1[dt][2*m]*rl1,   oa2 = a2[dt][2*m]*rl2;
      float ob1 = a1[dt][2*m+1]*rl1, ob2 = a2[dt][2*m+1]*rl2;
      float oa = oa1 + sh*(oa2-oa1);
      float ob = ob1 + sh*(ob2-ob1);
      int d = dt*32 + (2*m&3) + 8*(m>>1) + 4*l5;
      *(u32*)(obase + d) = cvtpk(oa, ob);
    }
  }
}

extern "C" void kernel_launch(void* const* d_in, const int* in_sizes, int n_in,
                              void* d_out, int out_size, void* d_ws, size_t ws_size,
                              hipStream_t stream){
  (void)in_sizes; (void)n_in; (void)out_size; (void)ws_size;
  const float* x   = (const float*)d_in[0];
  const float* Wq  = (const float*)d_in[1];
  const float* Wk  = (const float*)d_in[2];
  const float* Wv  = (const float*)d_in[3];
  const float* Wo  = (const float*)d_in[4];
  const float* lng = (const float*)d_in[5];
  const float* lnb = (const float*)d_in[6];
  const float* hsc = (const float*)d_in[7];
  const float* hdr = (const float*)d_in[8];

  char* ws = (char*)d_ws;
  const size_t MB = 1048576;
  u16* xn   = (u16*)ws;                 // 16MB (LN out, later attn out)
  u16* wbf  = (u16*)(ws + 16*MB);       // 8MB bf16 weights
  u16* Qb   = (u16*)(ws + 24*MB);       // 16MB
  u16* Kb   = (u16*)(ws + 40*MB);       // 16MB raw K (staging)
  u16* VF   = (u16*)(ws + 56*MB);       // 16MB packed V fragments
  u16* KF   = (u16*)(ws + 72*MB);       // 16MB packed K fragments
  float* cosT = (float*)(ws + 88*MB);
  float* sinT = cosT + 131072;
  float* qp   = sinT + 131072;
  float* kp   = qp + 65536;

  ln_k<<<8192,256,0,stream>>>(x, lng, lnb, xn);
  wconv_k<<<4096,256,0,stream>>>(Wq,Wk,Wv,Wo,wbf);
  rope_tab_k<<<512,256,0,stream>>>(cosT,sinT);
  gemm_k<0><<<dim3(64,8),256,0,stream>>>(xn, wbf,          Qb, nullptr, nullptr);
  gemm_k<0><<<dim3(64,8),256,0,stream>>>(xn, wbf+1048576,  Kb, nullptr, nullptr);
  gemm_k<4><<<dim3(64,8),256,0,stream>>>(xn, wbf+2097152,  VF, nullptr, nullptr);
  qpkp_k<<<256,256,0,stream>>>(Qb,Kb,hdr,cosT,sinT,qp,kp);          // raw Q/K + local rope
  ropepack_k<<<8192,128,0,stream>>>(Qb,Kb,KF,cosT,sinT);            // Q in place; K -> KF
  attn_k<<<1024,128,0,stream>>>(Qb,KF,VF,qp,kp,hsc,xn);
  gemm_k<2><<<dim3(64,8),256,0,stream>>>(xn, wbf+3145728, nullptr, (float*)d_out, x);
}

// Round 8
// 276.296 us; speedup vs baseline: 4.1346x; 3.7937x over previous
//
#include <hip/hip_runtime.h>
#include <hip/hip_bf16.h>
#include <stdint.h>

#define BB 4
#define TT 2048
#define CC 1024
#define HH 8
#define DD 128

typedef unsigned short u16;
typedef unsigned int u32;
typedef unsigned long long u64;
typedef __attribute__((ext_vector_type(4))) float f32x4;
typedef __attribute__((ext_vector_type(16))) float f32x16;
typedef __attribute__((ext_vector_type(8))) __bf16 bf16x8;

__device__ __forceinline__ float bf2f(u16 u){ u32 x=((u32)u)<<16; float f; __builtin_memcpy(&f,&x,4); return f; }
__device__ __forceinline__ u16 f2bf(float f){ u32 x; __builtin_memcpy(&x,&f,4); x += 0x7fffu + ((x>>16)&1u); return (u16)(x>>16); }

__device__ __forceinline__ void gload16(const void* g, void* l){
  __builtin_amdgcn_global_load_lds((const __attribute__((address_space(1))) u32*)g,
                                   (__attribute__((address_space(3))) u32*)l, 16, 0, 0);
}
__device__ __forceinline__ f32x4 mfma16(bf16x8 a, bf16x8 b, f32x4 c){
  return __builtin_amdgcn_mfma_f32_16x16x32_bf16(a,b,c,0,0,0);
}
__device__ __forceinline__ f32x16 mfma32(bf16x8 a, bf16x8 b, f32x16 c){
  return __builtin_amdgcn_mfma_f32_32x32x16_bf16(a,b,c,0,0,0);
}
__device__ __forceinline__ u32 cvtpk(float lo, float hi){
  u32 r; asm("v_cvt_pk_bf16_f32 %0, %1, %2" : "=v"(r) : "v"(lo), "v"(hi)); return r;
}
__device__ __forceinline__ void pl32swap(u32& d, u32& s){
  asm volatile("v_permlane32_swap_b32 %0, %1" : "+v"(d), "+v"(s));
}
union FRAG { u32 u[4]; bf16x8 v; };

// ---------------- LayerNorm: f32 x -> bf16 xn ----------------
__global__ void ln_k(const float* __restrict__ x, const float* __restrict__ g,
                     const float* __restrict__ bta, u16* __restrict__ xn){
  int row = blockIdx.x, tid = threadIdx.x;
  const float4 v = ((const float4*)(x + (size_t)row*CC))[tid];
  float s = v.x+v.y+v.z+v.w;
  float ss = v.x*v.x+v.y*v.y+v.z*v.z+v.w*v.w;
  #pragma unroll
  for(int m=1;m<64;m<<=1){ s += __shfl_xor(s,m); ss += __shfl_xor(ss,m); }
  __shared__ float red[8];
  if((tid&63)==0){ red[tid>>6]=s; red[4+(tid>>6)]=ss; }
  __syncthreads();
  float ts = red[0]+red[1]+red[2]+red[3];
  float tss = red[4]+red[5]+red[6]+red[7];
  float mu = ts*(1.0f/CC);
  float rs = rsqrtf(tss*(1.0f/CC) - mu*mu + 1e-5f);
  int c0 = tid*4;
  ushort4 o;
  o.x = f2bf((v.x-mu)*rs*g[c0+0]+bta[c0+0]);
  o.y = f2bf((v.y-mu)*rs*g[c0+1]+bta[c0+1]);
  o.z = f2bf((v.z-mu)*rs*g[c0+2]+bta[c0+2]);
  o.w = f2bf((v.w-mu)*rs*g[c0+3]+bta[c0+3]);
  ((ushort4*)(xn + (size_t)row*CC))[tid] = o;
}

// ---------------- weights f32 -> bf16 ----------------
__global__ void wconv_k(const float* __restrict__ wq, const float* __restrict__ wk,
                        const float* __restrict__ wv, const float* __restrict__ wo,
                        u16* __restrict__ out){
  int i = blockIdx.x*256 + threadIdx.x;
  int sel = i>>18;
  const float* src = sel==0?wq: sel==1?wk: sel==2?wv:wo;
  float4 v = ((const float4*)src)[i & 262143];
  ushort4 o; o.x=f2bf(v.x); o.y=f2bf(v.y); o.z=f2bf(v.z); o.w=f2bf(v.w);
  ((ushort4*)out)[i] = o;
}

// ---------------- RoPE tables ----------------
__global__ void rope_tab_k(float* __restrict__ cosT, float* __restrict__ sinT){
  int i = blockIdx.x*256 + threadIdx.x;
  int t = i>>6, j = i&63;
  float inv = powf(10000.0f, -(float)(2*j)*(1.0f/128.0f));
  float a = (float)t * inv;
  cosT[i] = cosf(a);
  sinT[i] = sinf(a);
}

// ---------------- qp/kp from RAW Q,K (rope applied locally to dims 0..2) ----------------
__global__ void qpkp_k(const u16* __restrict__ Qb, const u16* __restrict__ Kb,
                       const float* __restrict__ dirs, const float* __restrict__ cosT,
                       const float* __restrict__ sinT, float* __restrict__ qp, float* __restrict__ kp){
  int idx = blockIdx.x*256 + threadIdx.x;   // (b*H+h)*T + t
  int b = idx>>14, rem = idx & 16383;
  int h = rem>>11, t = rem & 2047;
  size_t base = ((size_t)(b*TT + t))*CC + h*DD;
  float qv = 0.f, kv = 0.f;
  #pragma unroll
  for(int d=0; d<3; d++){
    float c = cosT[t*64+d], s = sinT[t*64+d];
    float dr = dirs[h*3+d];
    qv += (bf2f(Qb[base+d])*c - bf2f(Qb[base+d+64])*s) * dr;
    kv += (bf2f(Kb[base+d])*c - bf2f(Kb[base+d+64])*s) * dr;
  }
  qp[idx] = qv; kp[idx] = kv;
}

// ---------------- RoPE: Q in place; K rope + pack into fragment-ordered KF ----------------
// KF u16 idx = ((bh*64 + ks)*8 + (d>>4))*512 + (((d>>3)&1)*32 + k31)*8 + (d&7)
__global__ void ropepack_k(u16* __restrict__ Qb, const u16* __restrict__ Kb,
                           u16* __restrict__ KF,
                           const float* __restrict__ cosT, const float* __restrict__ sinT){
  int bt = blockIdx.x, tid = threadIdx.x;   // 8192 x 128
  int b = bt>>11, t = bt & (TT-1);
  int ks = t>>5, k31 = t&31;
  #pragma unroll
  for(int pp=0; pp<4; pp++){
    int p = tid*4+pp;          // 0..511 = (h, d<64)
    int h = p>>6, d = p&63;
    size_t i1 = (size_t)bt*CC + h*DD + d;
    float c = cosT[t*64+d], s = sinT[t*64+d];
    float q1 = bf2f(Qb[i1]), q2 = bf2f(Qb[i1+64]);
    Qb[i1]    = f2bf(q1*c - q2*s);
    Qb[i1+64] = f2bf(q2*c + q1*s);
    float k1 = bf2f(Kb[i1]), k2 = bf2f(Kb[i1+64]);
    u16 kr1 = f2bf(k1*c - k2*s);
    u16 kr2 = f2bf(k2*c + k1*s);
    int bh = b*HH + h;
    int d2 = d + 64;
    size_t o1 = (((size_t)(bh*64 + ks)*8) + (d >>4))*512 + (((d >>3)&1)*32 + k31)*8 + (d &7);
    size_t o2 = (((size_t)(bh*64 + ks)*8) + (d2>>4))*512 + (((d2>>3)&1)*32 + k31)*8 + (d2&7);
    KF[o1] = kr1;
    KF[o2] = kr2;
  }
}

// ---------------- GEMM ----------------
// MODE 0: bf16 row-major out. MODE 4: bf16 out packed to V-fragment order VF. MODE 2: f32 out + resid.
template<int MODE>
__global__ __launch_bounds__(256) void gemm_k(const u16* __restrict__ A, const u16* __restrict__ W,
                                              u16* __restrict__ outb, float* __restrict__ outf,
                                              const float* __restrict__ resid){
  __shared__ __align__(16) u16 As[128*64];
  __shared__ __align__(16) u16 Bs[128*64];
  const int K = CC;
  int m0 = blockIdx.x*128, n0 = blockIdx.y*128;
  int tid = threadIdx.x, w = tid>>6, l = tid&63;
  int li = l&15, lg = l>>4;
  int wm = w>>1, wn = w&1;
  f32x4 acc[4][4] = {};
  for(int k0=0; k0<K; k0+=64){
    #pragma unroll
    for(int i=0;i<4;i++){
      int L = (w*4+i)*1024 + l*16;
      int row = L>>7;
      int colb = (L&127) ^ ((row&7)<<4);
      gload16(A + ((size_t)(m0+row)*K + k0 + (colb>>1)), (char*)As + (w*4+i)*1024);
      gload16(W + ((size_t)(n0+row)*K + k0 + (colb>>1)), (char*)Bs + (w*4+i)*1024);
    }
    __syncthreads();
    #pragma unroll
    for(int kc=0;kc<2;kc++){
      bf16x8 af[4], bfr[4];
      #pragma unroll
      for(int mi=0;mi<4;mi++){
        int row = wm*64 + mi*16 + li;
        int colb = (kc*64 + lg*16) ^ ((row&7)<<4);
        af[mi] = *(const bf16x8*)((const char*)As + row*128 + colb);
      }
      #pragma unroll
      for(int ni=0;ni<4;ni++){
        int row = wn*64 + ni*16 + li;
        int colb = (kc*64 + lg*16) ^ ((row&7)<<4);
        bfr[ni] = *(const bf16x8*)((const char*)Bs + row*128 + colb);
      }
      #pragma unroll
      for(int mi=0;mi<4;mi++){
        #pragma unroll
        for(int ni=0;ni<4;ni++)
          acc[mi][ni] = mfma16(af[mi], bfr[ni], acc[mi][ni]);
      }
    }
    __syncthreads();
  }
  #pragma unroll
  for(int mi=0;mi<4;mi++){
    #pragma unroll
    for(int ni=0;ni<4;ni++){
      #pragma unroll
      for(int r=0;r<4;r++){
        int row = m0 + wm*64 + mi*16 + lg*4 + r;
        int col = n0 + wn*64 + ni*16 + li;
        float v = acc[mi][ni][r];
        if(MODE==0){
          outb[(size_t)row*CC + col] = f2bf(v);
        } else if(MODE==4){
          // V-fragment pack: VF[((bh*64+ks)*8 + (d>>5)*2 + ((t>>4)&1))*512 + (((t>>3)&1)*32 + (d&31))*8 + (t&7)]
          int t = row & 2047, b = row>>11;
          int h = col>>7, d = col&127;
          int bh = b*HH + h;
          size_t o = (((size_t)(bh*64 + (t>>5))*8) + (d>>5)*2 + ((t>>4)&1))*512
                     + (((t>>3)&1)*32 + (d&31))*8 + (t&7);
          outb[o] = f2bf(v);
        } else {
          size_t o = (size_t)row*CC + col;
          outf[o] = v + resid[o];
        }
      }
    }
  }
}

// ---------------- fused dual flash attention: R4 structure + fragment-packed K/V ----------------
// 1024 blocks x 128 thr (2 waves). Block -> (bh, strip of 64 q); wave w owns 32 q.
// All K/V loads are contiguous 1KB bursts from the fragment-ordered KF/VF buffers.
// NOTE: __launch_bounds__(128,2) NOT (128,3): 3 waves/EU caps VGPR+AGPR at ~170 and
// spills the f32x16 accumulators to scratch (R6/R7: 2.3GB HBM writes, 5x slowdown).
__global__ __launch_bounds__(128,2) void attn_k(const u16* __restrict__ Q, const u16* __restrict__ KF,
                                                const u16* __restrict__ VF, const float* __restrict__ qp,
                                                const float* __restrict__ kp, const float* __restrict__ hs,
                                                u16* __restrict__ outp){
  int bid = blockIdx.x;
  int xcd = bid&7, r = bid>>3;          // r: 0..127
  int bh = xcd*4 + (r&3);               // 4 bh groups per XCD (K/V L2-resident)
  int strip = 31 - (r>>2);              // 31..0: longest strips dispatch first
  int b = bh>>3, h = bh&7;
  int tid = threadIdx.x, w = tid>>6, l = tid&63;
  int l5 = l>>5, q31 = l&31;
  int q0 = strip*64 + w*32;
  int q  = q0 + q31;
  int nsub = (q0>>5) + 1;               // 32-k subtiles this wave needs

  // Q fragment (B-operand): outer q, contraction d
  bf16x8 qf[8];
  {
    const u16* qbase = Q + ((size_t)(b*TT + q)*CC + h*DD);
    #pragma unroll
    for(int db=0;db<8;db++) qf[db] = *(const bf16x8*)(qbase + db*16 + l5*8);
  }
  const float L2E = 1.442695040888963f;
  const float sl2 = 0.08838834764831845f * L2E;
  bf16x8 qpf;
  {
    float qs = qp[(size_t)bh*TT + q] * L2E;
    u16 qh = f2bf(qs); float qhf = bf2f(qh);
    u16 ql = f2bf(qs - qhf);
    FRAG fq; fq.u[0] = l5? 0u : ((u32)qh | ((u32)qh<<16));
    fq.u[1] = l5? 0u : (u32)ql; fq.u[2]=0; fq.u[3]=0;
    qpf = fq.v;
  }

  // fragment-stream pointers: 4096 u16 (8KB) per subtile per buffer
  const u16* kfp = KF + (size_t)bh*64*4096 + (size_t)l*8;
  const u16* vfp = VF + (size_t)bh*64*4096 + (size_t)l*8;
  const float* kpp = kp + (size_t)bh*TT + q31;

  float m1=-__builtin_inff(), l1=0.f, m2=-__builtin_inff(), l2=0.f;
  f32x16 a1[4] = {}, a2[4] = {};
  const f32x16 zf = {};

  for(int is=0; is<nsub; ++is){
    int ksub = is*32;

    // ---- K fragments: 8 contiguous 1KB bursts ----
    bf16x8 kf0 = *(const bf16x8*)(kfp + 0*512);
    bf16x8 kf1 = *(const bf16x8*)(kfp + 1*512);
    bf16x8 kf2 = *(const bf16x8*)(kfp + 2*512);
    bf16x8 kf3 = *(const bf16x8*)(kfp + 3*512);
    bf16x8 kf4 = *(const bf16x8*)(kfp + 4*512);
    bf16x8 kf5 = *(const bf16x8*)(kfp + 5*512);
    bf16x8 kf6 = *(const bf16x8*)(kfp + 6*512);
    bf16x8 kf7 = *(const bf16x8*)(kfp + 7*512);

    // ---- S^T = K·Q^T (two independent chains) ----
    f32x16 s0 = zf, s1a = zf;
    __builtin_amdgcn_s_setprio(1);
    s0  = mfma32(kf0, qf[0], s0);  s1a = mfma32(kf1, qf[1], s1a);
    s0  = mfma32(kf2, qf[2], s0);  s1a = mfma32(kf3, qf[3], s1a);
    s0  = mfma32(kf4, qf[4], s0);  s1a = mfma32(kf5, qf[5], s1a);
    s0  = mfma32(kf6, qf[6], s0);  s1a = mfma32(kf7, qf[7], s1a);
    __builtin_amdgcn_s_setprio(0);

    // ---- geo scores via rank-1 mfma (hi/lo split, log2 domain) ----
    f32x16 gg;
    {
      float kpv = kpp[ksub];
      u16 kh = f2bf(kpv); float khf = bf2f(kh);
      u16 kl = f2bf(kpv - khf);
      FRAG fk; fk.u[0] = l5? 0u : ((u32)kh | ((u32)kl<<16));
      fk.u[1] = l5? 0u : (u32)kh; fk.u[2]=0; fk.u[3]=0;
      gg = mfma32(fk.v, qpf, zf);
    }

    // ---- scale (+ causal mask only on the diagonal subtile) ----
    float sv[16], gv[16];
    #pragma unroll
    for(int rr=0;rr<16;rr++){ sv[rr] = (s0[rr]+s1a[rr])*sl2; gv[rr] = gg[rr]; }
    if(ksub + 31 > q0){                       // wave-uniform diagonal test
      #pragma unroll
      for(int rr=0;rr<16;rr++){
        int kg = ksub + (rr&3) + 8*(rr>>2) + 4*l5;
        if(kg > q){ sv[rr] = -__builtin_inff(); gv[rr] = -__builtin_inff(); }
      }
    }

    // ---- dual online softmax, lane-local q, defer-max (THR=8 in log2) ----
    float mx=-__builtin_inff(), gx=-__builtin_inff();
    #pragma unroll
    for(int rr=0;rr<16;rr++){ mx = fmaxf(mx, sv[rr]); gx = fmaxf(gx, gv[rr]); }
    mx = fmaxf(mx, __shfl_xor(mx,32));
    gx = fmaxf(gx, __shfl_xor(gx,32));
    if(__ballot((mx > m1+8.f) | (gx > m2+8.f))){
      float mn1 = fmaxf(m1,mx), mn2 = fmaxf(m2,gx);
      float c1 = exp2f(m1-mn1), c2 = exp2f(m2-mn2);
      l1 *= c1; l2 *= c2; m1 = mn1; m2 = mn2;
      #pragma unroll
      for(int dt=0;dt<4;dt++){ a1[dt] *= c1; a2[dt] *= c2; }
    }
    float rs1=0.f, rs2=0.f;
    float e1[16], e2[16];
    #pragma unroll
    for(int rr=0;rr<16;rr++){
      e1[rr] = exp2f(sv[rr] - m1); rs1 += e1[rr];
      e2[rr] = exp2f(gv[rr] - m2); rs2 += e2[rr];
    }
    rs1 += __shfl_xor(rs1,32); rs2 += __shfl_xor(rs2,32);
    l1 += rs1; l2 += rs2;

    // ---- P -> bf16 B-fragments in-register ----
    u32 P1[8], P2[8];
    #pragma unroll
    for(int m=0;m<8;m++){ P1[m] = cvtpk(e1[2*m], e1[2*m+1]); P2[m] = cvtpk(e2[2*m], e2[2*m+1]); }
    pl32swap(P1[0],P1[2]); pl32swap(P1[1],P1[3]); pl32swap(P1[4],P1[6]); pl32swap(P1[5],P1[7]);
    pl32swap(P2[0],P2[2]); pl32swap(P2[1],P2[3]); pl32swap(P2[4],P2[6]); pl32swap(P2[5],P2[7]);

    // ---- O^T += V^T · P^T (V fragments: contiguous 1KB bursts) ----
    #pragma unroll
    for(int kb2=0;kb2<2;kb2++){
      FRAG f1, f2;
      #pragma unroll
      for(int j2=0;j2<4;j2++){ f1.u[j2] = P1[kb2*4+j2]; f2.u[j2] = P2[kb2*4+j2]; }
      bf16x8 pb1 = f1.v, pb2 = f2.v;
      bf16x8 vf0 = *(const bf16x8*)(vfp + (0+kb2)*512);
      bf16x8 vf1 = *(const bf16x8*)(vfp + (2+kb2)*512);
      bf16x8 vf2 = *(const bf16x8*)(vfp + (4+kb2)*512);
      bf16x8 vf3 = *(const bf16x8*)(vfp + (6+kb2)*512);
      __builtin_amdgcn_s_setprio(1);
      a1[0] = mfma32(vf0, pb1, a1[0]);  a2[0] = mfma32(vf0, pb2, a2[0]);
      a1[1] = mfma32(vf1, pb1, a1[1]);  a2[1] = mfma32(vf1, pb2, a2[1]);
      a1[2] = mfma32(vf2, pb1, a1[2]);  a2[2] = mfma32(vf2, pb2, a2[2]);
      a1[3] = mfma32(vf3, pb1, a1[3]);  a2[3] = mfma32(vf3, pb2, a2[3]);
      __builtin_amdgcn_s_setprio(0);
    }
    kfp += 4096; vfp += 4096;
  }

  float rl1 = 1.0f/l1, rl2 = 1.0f/l2;
  float sh = hs[h];
  u16* obase = outp + (size_t)(b*TT + q)*CC + h*DD;
  #pragma unroll
  for(int dt=0;dt<4;dt++){
    #pragma unroll
    for(int m=0;m<8;m++){
      float oa1 = a1[dt][2*m]*rl1,   oa2 = a2[dt][2*m]*rl2;
      float ob1 = a1[dt][2*m+1]*rl1, ob2 = a2[dt][2*m+1]*rl2;
      float oa = oa1 + sh*(oa2-oa1);
      float ob = ob1 + sh*(ob2-ob1);
      int d = dt*32 + (2*m&3) + 8*(m>>1) + 4*l5;
      *(u32*)(obase + d) = cvtpk(oa, ob);
    }
  }
}

extern "C" void kernel_launch(void* const* d_in, const int* in_sizes, int n_in,
                              void* d_out, int out_size, void* d_ws, size_t ws_size,
                              hipStream_t stream){
  (void)in_sizes; (void)n_in; (void)out_size; (void)ws_size;
  const float* x   = (const float*)d_in[0];
  const float* Wq  = (const float*)d_in[1];
  const float* Wk  = (const float*)d_in[2];
  const float* Wv  = (const float*)d_in[3];
  const float* Wo  = (const float*)d_in[4];
  const float* lng = (const float*)d_in[5];
  const float* lnb = (const float*)d_in[6];
  const float* hsc = (const float*)d_in[7];
  const float* hdr = (const float*)d_in[8];

  char* ws = (char*)d_ws;
  const size_t MB = 1048576;
  u16* xn   = (u16*)ws;                 // 16MB (LN out, later attn out)
  u16* wbf  = (u16*)(ws + 16*MB);       // 8MB bf16 weights
  u16* Qb   = (u16*)(ws + 24*MB);       // 16MB
  u16* Kb   = (u16*)(ws + 40*MB);       // 16MB raw K (staging)
  u16* VF   = (u16*)(ws + 56*MB);       // 16MB packed V fragments
  u16* KF   = (u16*)(ws + 72*MB);       // 16MB packed K fragments
  float* cosT = (float*)(ws + 88*MB);
  float* sinT = cosT + 131072;
  float* qp   = sinT + 131072;
  float* kp   = qp + 65536;

  ln_k<<<8192,256,0,stream>>>(x, lng, lnb, xn);
  wconv_k<<<4096,256,0,stream>>>(Wq,Wk,Wv,Wo,wbf);
  rope_tab_k<<<512,256,0,stream>>>(cosT,sinT);
  gemm_k<0><<<dim3(64,8),256,0,stream>>>(xn, wbf,          Qb, nullptr, nullptr);
  gemm_k<0><<<dim3(64,8),256,0,stream>>>(xn, wbf+1048576,  Kb, nullptr, nullptr);
  gemm_k<4><<<dim3(64,8),256,0,stream>>>(xn, wbf+2097152,  VF, nullptr, nullptr);
  qpkp_k<<<256,256,0,stream>>>(Qb,Kb,hdr,cosT,sinT,qp,kp);          // raw Q/K + local rope
  ropepack_k<<<8192,128,0,stream>>>(Qb,Kb,KF,cosT,sinT);            // Q in place; K -> KF
  attn_k<<<1024,128,0,stream>>>(Qb,KF,VF,qp,kp,hsc,xn);
  gemm_k<2><<<dim3(64,8),256,0,stream>>>(xn, wbf+3145728, nullptr, (float*)d_out, x);
}

// Round 9
// 231.630 us; speedup vs baseline: 4.9320x; 1.1928x over previous
//
#include <hip/hip_runtime.h>
#include <hip/hip_bf16.h>
#include <stdint.h>

#define BB 4
#define TT 2048
#define CC 1024
#define HH 8
#define DD 128

typedef unsigned short u16;
typedef unsigned int u32;
typedef unsigned long long u64;
typedef __attribute__((ext_vector_type(4))) float f32x4;
typedef __attribute__((ext_vector_type(16))) float f32x16;
typedef __attribute__((ext_vector_type(8))) __bf16 bf16x8;

__device__ __forceinline__ float bf2f(u16 u){ u32 x=((u32)u)<<16; float f; __builtin_memcpy(&f,&x,4); return f; }
__device__ __forceinline__ u16 f2bf(float f){ u32 x; __builtin_memcpy(&x,&f,4); x += 0x7fffu + ((x>>16)&1u); return (u16)(x>>16); }

__device__ __forceinline__ void gload16(const void* g, void* l){
  __builtin_amdgcn_global_load_lds((const __attribute__((address_space(1))) u32*)g,
                                   (__attribute__((address_space(3))) u32*)l, 16, 0, 0);
}
__device__ __forceinline__ f32x4 mfma16(bf16x8 a, bf16x8 b, f32x4 c){
  return __builtin_amdgcn_mfma_f32_16x16x32_bf16(a,b,c,0,0,0);
}
__device__ __forceinline__ f32x16 mfma32(bf16x8 a, bf16x8 b, f32x16 c){
  return __builtin_amdgcn_mfma_f32_32x32x16_bf16(a,b,c,0,0,0);
}
__device__ __forceinline__ u32 cvtpk(float lo, float hi){
  u32 r; asm("v_cvt_pk_bf16_f32 %0, %1, %2" : "=v"(r) : "v"(lo), "v"(hi)); return r;
}
__device__ __forceinline__ void pl32swap(u32& d, u32& s){
  asm volatile("v_permlane32_swap_b32 %0, %1" : "+v"(d), "+v"(s));
}
union FRAG { u32 u[4]; bf16x8 v; };

// ---------------- LayerNorm: f32 x -> bf16 xn ----------------
__global__ void ln_k(const float* __restrict__ x, const float* __restrict__ g,
                     const float* __restrict__ bta, u16* __restrict__ xn){
  int row = blockIdx.x, tid = threadIdx.x;
  const float4 v = ((const float4*)(x + (size_t)row*CC))[tid];
  float s = v.x+v.y+v.z+v.w;
  float ss = v.x*v.x+v.y*v.y+v.z*v.z+v.w*v.w;
  #pragma unroll
  for(int m=1;m<64;m<<=1){ s += __shfl_xor(s,m); ss += __shfl_xor(ss,m); }
  __shared__ float red[8];
  if((tid&63)==0){ red[tid>>6]=s; red[4+(tid>>6)]=ss; }
  __syncthreads();
  float ts = red[0]+red[1]+red[2]+red[3];
  float tss = red[4]+red[5]+red[6]+red[7];
  float mu = ts*(1.0f/CC);
  float rs = rsqrtf(tss*(1.0f/CC) - mu*mu + 1e-5f);
  int c0 = tid*4;
  ushort4 o;
  o.x = f2bf((v.x-mu)*rs*g[c0+0]+bta[c0+0]);
  o.y = f2bf((v.y-mu)*rs*g[c0+1]+bta[c0+1]);
  o.z = f2bf((v.z-mu)*rs*g[c0+2]+bta[c0+2]);
  o.w = f2bf((v.w-mu)*rs*g[c0+3]+bta[c0+3]);
  ((ushort4*)(xn + (size_t)row*CC))[tid] = o;
}

// ---------------- weights f32 -> bf16 ----------------
__global__ void wconv_k(const float* __restrict__ wq, const float* __restrict__ wk,
                        const float* __restrict__ wv, const float* __restrict__ wo,
                        u16* __restrict__ out){
  int i = blockIdx.x*256 + threadIdx.x;
  int sel = i>>18;
  const float* src = sel==0?wq: sel==1?wk: sel==2?wv:wo;
  float4 v = ((const float4*)src)[i & 262143];
  ushort4 o; o.x=f2bf(v.x); o.y=f2bf(v.y); o.z=f2bf(v.z); o.w=f2bf(v.w);
  ((ushort4*)out)[i] = o;
}

// ---------------- RoPE tables ----------------
__global__ void rope_tab_k(float* __restrict__ cosT, float* __restrict__ sinT){
  int i = blockIdx.x*256 + threadIdx.x;
  int t = i>>6, j = i&63;
  float inv = powf(10000.0f, -(float)(2*j)*(1.0f/128.0f));
  float a = (float)t * inv;
  cosT[i] = cosf(a);
  sinT[i] = sinf(a);
}

// ---------------- qp/kp from RAW Q,K (rope applied locally to dims 0..2) ----------------
__global__ void qpkp_k(const u16* __restrict__ Qb, const u16* __restrict__ Kb,
                       const float* __restrict__ dirs, const float* __restrict__ cosT,
                       const float* __restrict__ sinT, float* __restrict__ qp, float* __restrict__ kp){
  int idx = blockIdx.x*256 + threadIdx.x;   // (b*H+h)*T + t
  int b = idx>>14, rem = idx & 16383;
  int h = rem>>11, t = rem & 2047;
  size_t base = ((size_t)(b*TT + t))*CC + h*DD;
  float qv = 0.f, kv = 0.f;
  #pragma unroll
  for(int d=0; d<3; d++){
    float c = cosT[t*64+d], s = sinT[t*64+d];
    float dr = dirs[h*3+d];
    qv += (bf2f(Qb[base+d])*c - bf2f(Qb[base+d+64])*s) * dr;
    kv += (bf2f(Kb[base+d])*c - bf2f(Kb[base+d+64])*s) * dr;
  }
  qp[idx] = qv; kp[idx] = kv;
}

// ---------------- RoPE: Q in place; K rope + pack into fragment-ordered KF ----------------
// KF u16 idx = ((bh*64 + ks)*8 + (d>>4))*512 + (((d>>3)&1)*32 + k31)*8 + (d&7)
__global__ void ropepack_k(u16* __restrict__ Qb, const u16* __restrict__ Kb,
                           u16* __restrict__ KF,
                           const float* __restrict__ cosT, const float* __restrict__ sinT){
  int bt = blockIdx.x, tid = threadIdx.x;   // 8192 x 128
  int b = bt>>11, t = bt & (TT-1);
  int ks = t>>5, k31 = t&31;
  #pragma unroll
  for(int pp=0; pp<4; pp++){
    int p = tid*4+pp;          // 0..511 = (h, d<64)
    int h = p>>6, d = p&63;
    size_t i1 = (size_t)bt*CC + h*DD + d;
    float c = cosT[t*64+d], s = sinT[t*64+d];
    float q1 = bf2f(Qb[i1]), q2 = bf2f(Qb[i1+64]);
    Qb[i1]    = f2bf(q1*c - q2*s);
    Qb[i1+64] = f2bf(q2*c + q1*s);
    float k1 = bf2f(Kb[i1]), k2 = bf2f(Kb[i1+64]);
    u16 kr1 = f2bf(k1*c - k2*s);
    u16 kr2 = f2bf(k2*c + k1*s);
    int bh = b*HH + h;
    int d2 = d + 64;
    size_t o1 = (((size_t)(bh*64 + ks)*8) + (d >>4))*512 + (((d >>3)&1)*32 + k31)*8 + (d &7);
    size_t o2 = (((size_t)(bh*64 + ks)*8) + (d2>>4))*512 + (((d2>>3)&1)*32 + k31)*8 + (d2&7);
    KF[o1] = kr1;
    KF[o2] = kr2;
  }
}

// ---------------- GEMM ----------------
// MODE 0: bf16 row-major out. MODE 4: bf16 out packed to V-fragment order VF. MODE 2: f32 out + resid.
template<int MODE>
__global__ __launch_bounds__(256) void gemm_k(const u16* __restrict__ A, const u16* __restrict__ W,
                                              u16* __restrict__ outb, float* __restrict__ outf,
                                              const float* __restrict__ resid){
  __shared__ __align__(16) u16 As[128*64];
  __shared__ __align__(16) u16 Bs[128*64];
  const int K = CC;
  int m0 = blockIdx.x*128, n0 = blockIdx.y*128;
  int tid = threadIdx.x, w = tid>>6, l = tid&63;
  int li = l&15, lg = l>>4;
  int wm = w>>1, wn = w&1;
  f32x4 acc[4][4] = {};
  for(int k0=0; k0<K; k0+=64){
    #pragma unroll
    for(int i=0;i<4;i++){
      int L = (w*4+i)*1024 + l*16;
      int row = L>>7;
      int colb = (L&127) ^ ((row&7)<<4);
      gload16(A + ((size_t)(m0+row)*K + k0 + (colb>>1)), (char*)As + (w*4+i)*1024);
      gload16(W + ((size_t)(n0+row)*K + k0 + (colb>>1)), (char*)Bs + (w*4+i)*1024);
    }
    __syncthreads();
    #pragma unroll
    for(int kc=0;kc<2;kc++){
      bf16x8 af[4], bfr[4];
      #pragma unroll
      for(int mi=0;mi<4;mi++){
        int row = wm*64 + mi*16 + li;
        int colb = (kc*64 + lg*16) ^ ((row&7)<<4);
        af[mi] = *(const bf16x8*)((const char*)As + row*128 + colb);
      }
      #pragma unroll
      for(int ni=0;ni<4;ni++){
        int row = wn*64 + ni*16 + li;
        int colb = (kc*64 + lg*16) ^ ((row&7)<<4);
        bfr[ni] = *(const bf16x8*)((const char*)Bs + row*128 + colb);
      }
      #pragma unroll
      for(int mi=0;mi<4;mi++){
        #pragma unroll
        for(int ni=0;ni<4;ni++)
          acc[mi][ni] = mfma16(af[mi], bfr[ni], acc[mi][ni]);
      }
    }
    __syncthreads();
  }
  #pragma unroll
  for(int mi=0;mi<4;mi++){
    #pragma unroll
    for(int ni=0;ni<4;ni++){
      #pragma unroll
      for(int r=0;r<4;r++){
        int row = m0 + wm*64 + mi*16 + lg*4 + r;
        int col = n0 + wn*64 + ni*16 + li;
        float v = acc[mi][ni][r];
        if(MODE==0){
          outb[(size_t)row*CC + col] = f2bf(v);
        } else if(MODE==4){
          int t = row & 2047, b = row>>11;
          int h = col>>7, d = col&127;
          int bh = b*HH + h;
          size_t o = (((size_t)(bh*64 + (t>>5))*8) + (d>>5)*2 + ((t>>4)&1))*512
                     + (((t>>3)&1)*32 + (d&31))*8 + (t&7);
          outb[o] = f2bf(v);
        } else {
          size_t o = (size_t)row*CC + col;
          outf[o] = v + resid[o];
        }
      }
    }
  }
}

// ---------------- attention segment state + inner loop (R8-proven body) ----------------
struct SegState { float m1, l1, m2, l2; f32x16 a1[4]; f32x16 a2[4]; };

__device__ __forceinline__ void run_seg(int t, int klo, int khi, int bh, int b, int h,
                                        int l5, int q31,
                                        const u16* __restrict__ Q, const u16* __restrict__ KF,
                                        const u16* __restrict__ VF, const float* __restrict__ qp,
                                        const float* __restrict__ kp, SegState& S){
  const f32x16 zf = {};
  S.m1 = -__builtin_inff(); S.l1 = 0.f; S.m2 = -__builtin_inff(); S.l2 = 0.f;
  #pragma unroll
  for(int dt=0;dt<4;dt++){ S.a1[dt] = zf; S.a2[dt] = zf; }
  if(khi <= klo) return;

  int q0 = t*32, q = q0 + q31;
  bf16x8 qf[8];
  {
    const u16* qbase = Q + ((size_t)(b*TT + q)*CC + h*DD);
    #pragma unroll
    for(int db=0;db<8;db++) qf[db] = *(const bf16x8*)(qbase + db*16 + l5*8);
  }
  const float L2E = 1.442695040888963f;
  const float sl2 = 0.08838834764831845f * L2E;
  bf16x8 qpf;
  {
    float qs = qp[(size_t)bh*TT + q] * L2E;
    u16 qh = f2bf(qs); float qhf = bf2f(qh);
    u16 ql = f2bf(qs - qhf);
    FRAG fq; fq.u[0] = l5? 0u : ((u32)qh | ((u32)qh<<16));
    fq.u[1] = l5? 0u : (u32)ql; fq.u[2]=0; fq.u[3]=0;
    qpf = fq.v;
  }
  const u16* kfp = KF + (size_t)bh*64*4096 + (size_t)klo*4096 + (size_t)(q31 + 32*l5)*8;
  const u16* vfp = VF + (size_t)bh*64*4096 + (size_t)klo*4096 + (size_t)(q31 + 32*l5)*8;
  const float* kpp = kp + (size_t)bh*TT + q31;

  for(int is=klo; is<khi; ++is){
    int ksub = is*32;

    bf16x8 kf0 = *(const bf16x8*)(kfp + 0*512);
    bf16x8 kf1 = *(const bf16x8*)(kfp + 1*512);
    bf16x8 kf2 = *(const bf16x8*)(kfp + 2*512);
    bf16x8 kf3 = *(const bf16x8*)(kfp + 3*512);
    bf16x8 kf4 = *(const bf16x8*)(kfp + 4*512);
    bf16x8 kf5 = *(const bf16x8*)(kfp + 5*512);
    bf16x8 kf6 = *(const bf16x8*)(kfp + 6*512);
    bf16x8 kf7 = *(const bf16x8*)(kfp + 7*512);

    f32x16 s0 = zf, s1a = zf;
    __builtin_amdgcn_s_setprio(1);
    s0  = mfma32(kf0, qf[0], s0);  s1a = mfma32(kf1, qf[1], s1a);
    s0  = mfma32(kf2, qf[2], s0);  s1a = mfma32(kf3, qf[3], s1a);
    s0  = mfma32(kf4, qf[4], s0);  s1a = mfma32(kf5, qf[5], s1a);
    s0  = mfma32(kf6, qf[6], s0);  s1a = mfma32(kf7, qf[7], s1a);
    __builtin_amdgcn_s_setprio(0);

    f32x16 gg;
    {
      float kpv = kpp[ksub];
      u16 kh = f2bf(kpv); float khf = bf2f(kh);
      u16 kl = f2bf(kpv - khf);
      FRAG fk; fk.u[0] = l5? 0u : ((u32)kh | ((u32)kl<<16));
      fk.u[1] = l5? 0u : (u32)kh; fk.u[2]=0; fk.u[3]=0;
      gg = mfma32(fk.v, qpf, zf);
    }

    float sv[16], gv[16];
    #pragma unroll
    for(int rr=0;rr<16;rr++){ sv[rr] = (s0[rr]+s1a[rr])*sl2; gv[rr] = gg[rr]; }
    if(ksub + 31 > q0){                       // wave-uniform diagonal test
      #pragma unroll
      for(int rr=0;rr<16;rr++){
        int kg = ksub + (rr&3) + 8*(rr>>2) + 4*l5;
        if(kg > q){ sv[rr] = -__builtin_inff(); gv[rr] = -__builtin_inff(); }
      }
    }

    float mx=-__builtin_inff(), gx=-__builtin_inff();
    #pragma unroll
    for(int rr=0;rr<16;rr++){ mx = fmaxf(mx, sv[rr]); gx = fmaxf(gx, gv[rr]); }
    mx = fmaxf(mx, __shfl_xor(mx,32));
    gx = fmaxf(gx, __shfl_xor(gx,32));
    if(__ballot((mx > S.m1+8.f) | (gx > S.m2+8.f))){
      float mn1 = fmaxf(S.m1,mx), mn2 = fmaxf(S.m2,gx);
      float c1 = exp2f(S.m1-mn1), c2 = exp2f(S.m2-mn2);
      S.l1 *= c1; S.l2 *= c2; S.m1 = mn1; S.m2 = mn2;
      #pragma unroll
      for(int dt=0;dt<4;dt++){ S.a1[dt] *= c1; S.a2[dt] *= c2; }
    }
    float rs1=0.f, rs2=0.f;
    float e1[16], e2[16];
    #pragma unroll
    for(int rr=0;rr<16;rr++){
      e1[rr] = exp2f(sv[rr] - S.m1); rs1 += e1[rr];
      e2[rr] = exp2f(gv[rr] - S.m2); rs2 += e2[rr];
    }
    rs1 += __shfl_xor(rs1,32); rs2 += __shfl_xor(rs2,32);
    S.l1 += rs1; S.l2 += rs2;

    u32 P1[8], P2[8];
    #pragma unroll
    for(int m=0;m<8;m++){ P1[m] = cvtpk(e1[2*m], e1[2*m+1]); P2[m] = cvtpk(e2[2*m], e2[2*m+1]); }
    pl32swap(P1[0],P1[2]); pl32swap(P1[1],P1[3]); pl32swap(P1[4],P1[6]); pl32swap(P1[5],P1[7]);
    pl32swap(P2[0],P2[2]); pl32swap(P2[1],P2[3]); pl32swap(P2[4],P2[6]); pl32swap(P2[5],P2[7]);

    #pragma unroll
    for(int kb2=0;kb2<2;kb2++){
      FRAG f1, f2;
      #pragma unroll
      for(int j2=0;j2<4;j2++){ f1.u[j2] = P1[kb2*4+j2]; f2.u[j2] = P2[kb2*4+j2]; }
      bf16x8 pb1 = f1.v, pb2 = f2.v;
      bf16x8 vf0 = *(const bf16x8*)(vfp + (0+kb2)*512);
      bf16x8 vf1 = *(const bf16x8*)(vfp + (2+kb2)*512);
      bf16x8 vf2 = *(const bf16x8*)(vfp + (4+kb2)*512);
      bf16x8 vf3 = *(const bf16x8*)(vfp + (6+kb2)*512);
      __builtin_amdgcn_s_setprio(1);
      S.a1[0] = mfma32(vf0, pb1, S.a1[0]);  S.a2[0] = mfma32(vf0, pb2, S.a2[0]);
      S.a1[1] = mfma32(vf1, pb1, S.a1[1]);  S.a2[1] = mfma32(vf1, pb2, S.a2[1]);
      S.a1[2] = mfma32(vf2, pb1, S.a1[2]);  S.a2[2] = mfma32(vf2, pb2, S.a2[2]);
      S.a1[3] = mfma32(vf3, pb1, S.a1[3]);  S.a2[3] = mfma32(vf3, pb2, S.a2[3]);
      __builtin_amdgcn_s_setprio(0);
    }
    kfp += 4096; vfp += 4096;
  }
}

// ---------------- fused dual flash attention: pair-balanced waves + in-block LDS merge ----------------
// 1024 blocks x 128 (2 waves). Block = (bh, pair p). Wave0: tile p full (p+1) + tile 63-p k[0,31-p) -> 32 iters.
// Wave1: tile 63-p k[31-p,64-p) -> 33 iters. Tile 63-p merged via LDS (LSE-weighted), single barrier.
__global__ __launch_bounds__(128,2) void attn_k(const u16* __restrict__ Q, const u16* __restrict__ KF,
                                                const u16* __restrict__ VF, const float* __restrict__ qp,
                                                const float* __restrict__ kp, const float* __restrict__ hs,
                                                u16* __restrict__ outp){
  __shared__ __align__(16) float lp1[4*64*16];   // wave0's partial a1 [dt][lane][r]
  __shared__ __align__(16) float lp2[4*64*16];   // partial a2
  __shared__ float lml[32*4];                    // per q31: m1,l1,m2,l2
  int bid = blockIdx.x;
  int xcd = bid&7, r = bid>>3;          // r: 0..127
  int bh = xcd*4 + (r&3);               // 4 bh groups per XCD
  int p = r>>2;                         // 0..31 pair index
  int b = bh>>3, h = bh&7;
  int tid = threadIdx.x, w = tid>>6, l = tid&63;
  int l5 = l>>5, q31 = l&31;
  float sh = hs[h];

  SegState S;
  if(w==0){
    // seg0: tile p, full range, direct write
    run_seg(p, 0, p+1, bh, b, h, l5, q31, Q, KF, VF, qp, kp, S);
    {
      float rl1 = 1.0f/S.l1, rl2 = 1.0f/S.l2;
      int q = p*32 + q31;
      u16* obase = outp + (size_t)(b*TT + q)*CC + h*DD;
      #pragma unroll
      for(int dt=0;dt<4;dt++){
        #pragma unroll
        for(int m=0;m<8;m++){
          float oa1 = S.a1[dt][2*m]*rl1,   oa2 = S.a2[dt][2*m]*rl2;
          float ob1 = S.a1[dt][2*m+1]*rl1, ob2 = S.a2[dt][2*m+1]*rl2;
          float oa = oa1 + sh*(oa2-oa1);
          float ob = ob1 + sh*(ob2-ob1);
          int d = dt*32 + (2*m&3) + 8*(m>>1) + 4*l5;
          *(u32*)(obase + d) = cvtpk(oa, ob);
        }
      }
    }
    // seg1: tile 63-p, first half k[0, 31-p) -> partial to LDS
    run_seg(63-p, 0, 31-p, bh, b, h, l5, q31, Q, KF, VF, qp, kp, S);
    #pragma unroll
    for(int dt=0;dt<4;dt++){
      *(f32x16*)&lp1[(dt*64 + l)*16] = S.a1[dt];
      *(f32x16*)&lp2[(dt*64 + l)*16] = S.a2[dt];
    }
    if(l5==0){
      lml[q31*4+0] = S.m1; lml[q31*4+1] = S.l1;
      lml[q31*4+2] = S.m2; lml[q31*4+3] = S.l2;
    }
    __syncthreads();
  } else {
    // wave1: tile 63-p, second half k[31-p, 64-p)
    run_seg(63-p, 31-p, 64-p, bh, b, h, l5, q31, Q, KF, VF, qp, kp, S);
    __syncthreads();
    float mA1 = lml[q31*4+0], lA1 = lml[q31*4+1];
    float mA2 = lml[q31*4+2], lA2 = lml[q31*4+3];
    float M1 = fmaxf(mA1, S.m1), M2 = fmaxf(mA2, S.m2);
    float wA1 = exp2f(mA1-M1), wB1 = exp2f(S.m1-M1);
    float wA2 = exp2f(mA2-M2), wB2 = exp2f(S.m2-M2);
    float r1 = 1.0f/(wA1*lA1 + wB1*S.l1);
    float r2 = 1.0f/(wA2*lA2 + wB2*S.l2);
    int q = (63-p)*32 + q31;
    u16* obase = outp + (size_t)(b*TT + q)*CC + h*DD;
    #pragma unroll
    for(int dt=0;dt<4;dt++){
      f32x16 pa1 = *(const f32x16*)&lp1[(dt*64 + l)*16];
      f32x16 pa2 = *(const f32x16*)&lp2[(dt*64 + l)*16];
      #pragma unroll
      for(int m=0;m<8;m++){
        float oa1 = (wA1*pa1[2*m]   + wB1*S.a1[dt][2*m])*r1;
        float ob1 = (wA1*pa1[2*m+1] + wB1*S.a1[dt][2*m+1])*r1;
        float oa2 = (wA2*pa2[2*m]   + wB2*S.a2[dt][2*m])*r2;
        float ob2 = (wA2*pa2[2*m+1] + wB2*S.a2[dt][2*m+1])*r2;
        float oa = oa1 + sh*(oa2-oa1);
        float ob = ob1 + sh*(ob2-ob1);
        int d = dt*32 + (2*m&3) + 8*(m>>1) + 4*l5;
        *(u32*)(obase + d) = cvtpk(oa, ob);
      }
    }
  }
}

extern "C" void kernel_launch(void* const* d_in, const int* in_sizes, int n_in,
                              void* d_out, int out_size, void* d_ws, size_t ws_size,
                              hipStream_t stream){
  (void)in_sizes; (void)n_in; (void)out_size; (void)ws_size;
  const float* x   = (const float*)d_in[0];
  const float* Wq  = (const float*)d_in[1];
  const float* Wk  = (const float*)d_in[2];
  const float* Wv  = (const float*)d_in[3];
  const float* Wo  = (const float*)d_in[4];
  const float* lng = (const float*)d_in[5];
  const float* lnb = (const float*)d_in[6];
  const float* hsc = (const float*)d_in[7];
  const float* hdr = (const float*)d_in[8];

  char* ws = (char*)d_ws;
  const size_t MB = 1048576;
  u16* xn   = (u16*)ws;                 // 16MB (LN out, later attn out)
  u16* wbf  = (u16*)(ws + 16*MB);       // 8MB bf16 weights
  u16* Qb   = (u16*)(ws + 24*MB);       // 16MB
  u16* Kb   = (u16*)(ws + 40*MB);       // 16MB raw K (staging)
  u16* VF   = (u16*)(ws + 56*MB);       // 16MB packed V fragments
  u16* KF   = (u16*)(ws + 72*MB);       // 16MB packed K fragments
  float* cosT = (float*)(ws + 88*MB);
  float* sinT = cosT + 131072;
  float* qp   = sinT + 131072;
  float* kp   = qp + 65536;

  ln_k<<<8192,256,0,stream>>>(x, lng, lnb, xn);
  wconv_k<<<4096,256,0,stream>>>(Wq,Wk,Wv,Wo,wbf);
  rope_tab_k<<<512,256,0,stream>>>(cosT,sinT);
  gemm_k<0><<<dim3(64,8),256,0,stream>>>(xn, wbf,          Qb, nullptr, nullptr);
  gemm_k<0><<<dim3(64,8),256,0,stream>>>(xn, wbf+1048576,  Kb, nullptr, nullptr);
  gemm_k<4><<<dim3(64,8),256,0,stream>>>(xn, wbf+2097152,  VF, nullptr, nullptr);
  qpkp_k<<<256,256,0,stream>>>(Qb,Kb,hdr,cosT,sinT,qp,kp);          // raw Q/K + local rope
  ropepack_k<<<8192,128,0,stream>>>(Qb,Kb,KF,cosT,sinT);            // Q in place; K -> KF
  attn_k<<<1024,128,0,stream>>>(Qb,KF,VF,qp,kp,hsc,xn);
  gemm_k<2><<<dim3(64,8),256,0,stream>>>(xn, wbf+3145728, nullptr, (float*)d_out, x);
}